// Round 12
// baseline (30.342 us; speedup 1.0000x reference)
//
#include <hip/hip_runtime.h>

#define NB 4
#define NP 160
#define NL 128
#define NH 768
#define NT 9
#define NBLK (NB * NL)   // 512 producers (one per (b,l)); block 512 = consumer
#define L2E 1.4426950408889634f
#define LN2 0.6931471805599453f
#define MAGIC 0x5F3D2B19u

struct WS {
    float    lg[NBLK * NT];   // logits rows (agent-scope)
    float    part[NBLK];      // per-block slice mins (agent-scope)
    unsigned flags[NBLK];     // MAGIC = row ready; MAGIC+1 = ready, needs minv fixup.
                              // Consumer resets to 0 -> every call self-contained.
};

#define AST(p, v) __hip_atomic_store((p), (v), __ATOMIC_RELAXED, __HIP_MEMORY_SCOPE_AGENT)
#define ALD(p)    __hip_atomic_load((p), __ATOMIC_RELAXED, __HIP_MEMORY_SCOPE_AGENT)

__device__ __forceinline__ float rdlane(float v, int p) {
    return __int_as_float(__builtin_amdgcn_readlane(__float_as_int(v), p));
}

// Full-wave sum via DPP; result in lane 63.
__device__ __forceinline__ float dpp_add(float x) {
    float t;
#define STEP(ctrl, rmask, bc) \
    t = __int_as_float(__builtin_amdgcn_update_dpp(0, __float_as_int(x), ctrl, rmask, 0xf, bc)); \
    x += t;
    STEP(0x111, 0xf, true) STEP(0x112, 0xf, true) STEP(0x114, 0xf, true) STEP(0x118, 0xf, true)
    STEP(0x142, 0xa, false) STEP(0x143, 0xc, false)
#undef STEP
    return x;
}

// Full-wave min via DPP; result in lane 63.
__device__ __forceinline__ float dpp_fmin(float x) {
    float t;
#define STEP(ctrl, rmask) \
    t = __int_as_float(__builtin_amdgcn_update_dpp(__float_as_int(x), __float_as_int(x), ctrl, rmask, 0xf, false)); \
    x = fminf(x, t);
    STEP(0x111, 0xf) STEP(0x112, 0xf) STEP(0x114, 0xf) STEP(0x118, 0xf)
    STEP(0x142, 0xa) STEP(0x143, 0xc)
#undef STEP
    return x;
}

__device__ __forceinline__ float exp2v(float x) {
    float r; asm("v_exp_f32 %0, %1" : "=v"(r) : "v"(x)); return r;
}
__device__ __forceinline__ float log2v(float x) {
    float r; asm("v_log_f32 %0, %1" : "=v"(r) : "v"(x)); return r;
}

__global__ __launch_bounds__(256) void kfused(
    const float* __restrict__ embs, const void* __restrict__ p2w,
    const void* __restrict__ masks, const int* __restrict__ labels,
    const int* __restrict__ sentlen, const float* __restrict__ W,
    const float* __restrict__ bias, const float* __restrict__ start_t,
    const float* __restrict__ end_t, const float* __restrict__ trans,
    float* __restrict__ out, WS* __restrict__ ws)
{
    const int bl  = blockIdx.x;
    const int tid = threadIdx.x;
    const int w = tid >> 6, lane = tid & 63;

    if (bl < NBLK) {
        // ================= producer: R11 klogits verbatim + flag release =================
        const int b = bl / NL;

        __shared__ int   plist[NP];
        __shared__ int   cnt;
        __shared__ int   isint_sh;
        __shared__ float wmin[4];

        const float4* e4 = (const float4*)(embs + bl * 960);   // 512*960 = NB*NP*NH
        float4 mv4 = (tid < 240) ? e4[tid] : make_float4(3.0e38f, 3.0e38f, 3.0e38f, 3.0e38f);
        unsigned char pb = 0;
        if (tid < NP) pb = ((const unsigned char*)p2w)[bl * NP + tid];
        const unsigned char mkb = ((const unsigned char*)masks)[bl];

        // detect: masks word 0 (batch 0 all-true): int32 -> 1, bytes -> 0x01010101
        if (tid == 0) { isint_sh = (((const unsigned*)masks)[0] <= 1u); cnt = 0; }
        __syncthreads();
        const int is_int = isint_sh;

        int have = 0;
        if (tid < NP) have = is_int ? (((const int*)p2w)[bl * NP + tid] != 0) : (pb != 0);
        if (have) plist[atomicAdd(&cnt, 1)] = tid;   // nc <= 2 pieces/word

        float m = fminf(fminf(mv4.x, mv4.y), fminf(mv4.z, mv4.w));
        m = dpp_fmin(m);
        if (lane == 63) wmin[w] = m;

        const int mk = is_int ? (((const int*)masks)[bl] != 0) : (mkb != 0);
        __syncthreads();
        if (tid == 0) {
            float pm = fminf(fminf(wmin[0], wmin[1]), fminf(wmin[2], wmin[3]));
            AST(&ws->part[bl], pm);
        }

        const int nc = cnt;
        if (nc == 0) {
            // bias row (consumer overwrites if mk: minv fixup)
            if (tid < NT) {
                float v = bias[tid];
                out[1 + bl * NT + tid] = v;
                AST(&ws->lg[bl * NT + tid], v);
            }
        } else {
            // on-the-fly pooling fused into GEMV (R11-validated)
            float wr[12];
            #pragma unroll
            for (int j = 0; j < 12; j++) wr[j] = -3.0e38f;
            for (int i = 0; i < nc; i++) {
                const float* er = embs + (b * NP + plist[i]) * NH;
                #pragma unroll
                for (int j = 0; j < 12; j++) wr[j] = fmaxf(wr[j], er[lane + j * 64]);
            }
            const float mkf = mk ? 1.0f : 0.0f;
            for (int t = w; t < NT; t += 4) {
                float acc = 0.f;
                #pragma unroll
                for (int j = 0; j < 12; j++) acc += wr[j] * W[(lane + j * 64) * NT + t];
                acc = dpp_add(acc);
                if (lane == 63) {
                    float v = fmaf(mkf, acc, bias[t]);
                    out[1 + bl * NT + t] = v;
                    AST(&ws->lg[bl * NT + t], v);
                }
            }
        }

        // release: drain this wave's stores, join waves, set flag (distinct address/block)
        asm volatile("s_waitcnt vmcnt(0)" ::: "memory");
        __syncthreads();
        if (tid == 0) AST(&ws->flags[bl], MAGIC + ((nc == 0 && mk) ? 1u : 0u));
        return;
    }

    // ================= consumer (block 512): R11 kcrf math =================
    __shared__ float em_s[NB * NL * NT + 16];   // raw logits; pad covers prefetch overread
    __shared__ float trs[NT * NT];              // log2-scaled
    __shared__ int   lab_s[NB * NL];
    __shared__ float llh[NB];
    __shared__ float colsum[NT];
    __shared__ float wmin2[4];

    // prestage independent data while producers run
    if (tid < 128) ((int4*)lab_s)[tid] = ((const int4*)labels)[tid];
    if (tid < NT * NT) trs[tid] = trans[tid] * L2E;
    for (int t = w; t < NT; t += 4) {   // colsum(W) for minv fixup
        float s = 0.f;
        #pragma unroll
        for (int j = 0; j < 12; j++) s += W[(lane + j * 64) * NT + t];
        s = dpp_add(s);
        if (lane == 63) colsum[t] = s;
    }

    // wait for this call's producers (self-contained: works from any initial flag state)
    unsigned f0, f1;
    while ((f0 = ALD(&ws->flags[tid])) - MAGIC > 1u) __builtin_amdgcn_s_sleep(1);
    while ((f1 = ALD(&ws->flags[tid + 256])) - MAGIC > 1u) __builtin_amdgcn_s_sleep(1);
    __syncthreads();

    {   // global min from 512 partials
        float mv = fminf(ALD(&ws->part[tid]), ALD(&ws->part[tid + 256]));
        mv = dpp_fmin(mv);
        if (lane == 63) wmin2[w] = mv;
    }
    {   // stage logits: 8B agent loads (2304 u64, 9 rounds)
        const unsigned long long* lg8 = (const unsigned long long*)ws->lg;
        #pragma unroll
        for (int r = 0; r < 9; r++) {
            int i = tid + r * 256;
            unsigned long long v = ALD(&lg8[i]);
            em_s[2 * i]     = __int_as_float((unsigned)v);
            em_s[2 * i + 1] = __int_as_float((unsigned)(v >> 32));
        }
    }
    __syncthreads();
    const float minv = fminf(fminf(wmin2[0], wmin2[1]), fminf(wmin2[2], wmin2[3]));

    // fixup rows flagged MAGIC+1: minv*colsum + bias
    if (f0 == MAGIC + 1u) {
        #pragma unroll
        for (int t = 0; t < NT; t++) {
            float v = fmaf(minv, colsum[t], bias[t]);
            em_s[tid * NT + t]    = v;
            out[1 + tid * NT + t] = v;
        }
    }
    if (f1 == MAGIC + 1u) {
        const int r = tid + 256;
        #pragma unroll
        for (int t = 0; t < NT; t++) {
            float v = fmaf(minv, colsum[t], bias[t]);
            em_s[r * NT + t]    = v;
            out[1 + r * NT + t] = v;
        }
    }
    __syncthreads();

    // ---- CRF: 4 waves, one per batch; lanes 0..8 = tags; log2 domain, relative alpha ----
    {
        const int b   = w;
        const int c   = (lane < NT) ? lane : 0;
        const int len = sentlen[b];                 // masks == arange < sent_length
        const float* em  = em_s + b * NL * NT;
        const int*   lab = lab_s + b * NL;

        // numerator: fully parallel over positions
        float nsum = 0.f;
        for (int i = 1 + lane; i < len; i += 64) {
            int tp = lab[i - 1], tc = lab[i];
            nsum = fmaf(em[i * NT + tc], L2E, nsum + trs[tp * NT + tc]);
        }
        nsum = dpp_add(nsum);
        const float nsum_all = rdlane(nsum, 63);

        // serial recursion — log2 domain, RELATIVE alpha (R11-validated)
        float tcol[NT];
        #pragma unroll
        for (int p = 0; p < NT; p++) tcol[p] = trs[p * NT + c];
        const float ecol0 = exp2v(tcol[0]);

        float vini = fmaf(em[c], L2E, start_t[c] * L2E);
        float rv0  = rdlane(vini, 0);
        float wrel = vini - rv0;
        float a0abs = rv0;
        float r1 = rdlane(wrel, 1), r2 = rdlane(wrel, 2), r3 = rdlane(wrel, 3);
        float r4 = rdlane(wrel, 4), r5 = rdlane(wrel, 5), r6 = rdlane(wrel, 6);
        float r7 = rdlane(wrel, 7), r8 = rdlane(wrel, 8);

        float em_c = em[NT + c];
        for (int i = 1; i < len; i++) {
            float em_nx = em[(i + 1) * NT + c];   // pad covers overread at i = len-1
            float e1 = exp2v(r1 + tcol[1]);
            float e2 = exp2v(r2 + tcol[2]);
            float e3 = exp2v(r3 + tcol[3]);
            float e4 = exp2v(r4 + tcol[4]);
            float e5 = exp2v(r5 + tcol[5]);
            float e6 = exp2v(r6 + tcol[6]);
            float e7 = exp2v(r7 + tcol[7]);
            float e8 = exp2v(r8 + tcol[8]);
            float s = (((ecol0 + e1) + (e2 + e3)) + ((e4 + e5) + (e6 + e7))) + e8;
            float v = fmaf(em_c, L2E, log2v(s));
            float nv0 = rdlane(v, 0);
            wrel = v - nv0;
            r1 = rdlane(wrel, 1); r2 = rdlane(wrel, 2); r3 = rdlane(wrel, 3);
            r4 = rdlane(wrel, 4); r5 = rdlane(wrel, 5); r6 = rdlane(wrel, 6);
            r7 = rdlane(wrel, 7); r8 = rdlane(wrel, 8);
            a0abs += nv0;
            em_c = em_nx;
        }

        // denominator + loss
        float xv = wrel + end_t[c] * L2E;
        if (lane == 0) {
            float dv[NT];
            #pragma unroll
            for (int p = 0; p < NT; p++) dv[p] = rdlane(xv, p);
            float mx = fmaxf(fmaxf(fmaxf(dv[0], dv[1]), dv[2]),
                             fmaxf(fmaxf(fmaxf(dv[3], dv[4]), dv[5]),
                                   fmaxf(fmaxf(dv[6], dv[7]), dv[8])));
            float s = 0.f;
            #pragma unroll
            for (int p = 0; p < NT; p++) s += exp2v(dv[p] - mx);
            float den = a0abs + mx + log2v(s);
            int   t0  = lab[0];
            float num = fmaf(em[t0], L2E, nsum_all + start_t[t0] * L2E + end_t[lab[len - 1]] * L2E);
            llh[b] = (num - den) * LN2;
        }
    }
    __syncthreads();
    if (tid == 0) out[0] = -(llh[0] + llh[1] + llh[2] + llh[3]);

    // reset flags -> next call starts from a known state (self-contained calls)
    AST(&ws->flags[tid], 0u);
    AST(&ws->flags[tid + 256], 0u);
}

extern "C" void kernel_launch(void* const* d_in, const int* in_sizes, int n_in,
                              void* d_out, int out_size, void* d_ws, size_t ws_size,
                              hipStream_t stream) {
    const float* embs    = (const float*)d_in[0];
    const void*  p2w     = d_in[1];
    const void*  masks   = d_in[2];
    const int*   labels  = (const int*)d_in[3];
    const int*   sentlen = (const int*)d_in[4];
    const float* W       = (const float*)d_in[5];
    const float* bias    = (const float*)d_in[6];
    const float* start_t = (const float*)d_in[7];
    const float* end_t   = (const float*)d_in[8];
    const float* trans   = (const float*)d_in[9];

    float* out = (float*)d_out;        // out[0] = loss, out[1..] = logits (B,L,T)
    WS*    ws  = (WS*)d_ws;

    kfused<<<NBLK + 1, 256, 0, stream>>>(embs, p2w, masks, labels, sentlen, W, bias,
                                         start_t, end_t, trans, out, ws);
}

// Round 13
// 29.454 us; speedup vs baseline: 1.0302x; 1.0302x over previous
//
#include <hip/hip_runtime.h>

#define NB 4
#define NP 160
#define NL 128
#define NH 768
#define NT 9
#define NBLK (NB * NL)   // 512, one block per (b,l)
#define L2E 1.4426950408889634f
#define LN2 0.6931471805599453f

struct WS {
    float lg[NBLK * NT];   // 16B-aligned logits copy for fast kcrf staging
    float part[NBLK];      // per-block slice mins of embs
    int   empty[NBLK];     // 1 = empty-but-masked row (needs minv fixup in kcrf)
};

__device__ __forceinline__ float rdlane(float v, int p) {
    return __int_as_float(__builtin_amdgcn_readlane(__float_as_int(v), p));
}

// Full-wave sum via DPP; result in lane 63.
__device__ __forceinline__ float dpp_add(float x) {
    float t;
#define STEP(ctrl, rmask, bc) \
    t = __int_as_float(__builtin_amdgcn_update_dpp(0, __float_as_int(x), ctrl, rmask, 0xf, bc)); \
    x += t;
    STEP(0x111, 0xf, true) STEP(0x112, 0xf, true) STEP(0x114, 0xf, true) STEP(0x118, 0xf, true)
    STEP(0x142, 0xa, false) STEP(0x143, 0xc, false)
#undef STEP
    return x;
}

// Full-wave min via DPP; result in lane 63.
__device__ __forceinline__ float dpp_fmin(float x) {
    float t;
#define STEP(ctrl, rmask) \
    t = __int_as_float(__builtin_amdgcn_update_dpp(__float_as_int(x), __float_as_int(x), ctrl, rmask, 0xf, false)); \
    x = fminf(x, t);
    STEP(0x111, 0xf) STEP(0x112, 0xf) STEP(0x114, 0xf) STEP(0x118, 0xf)
    STEP(0x142, 0xa) STEP(0x143, 0xc)
#undef STEP
    return x;
}

__device__ __forceinline__ float exp2v(float x) {
    float r; asm("v_exp_f32 %0, %1" : "=v"(r) : "v"(x)); return r;
}
__device__ __forceinline__ float log2v(float x) {
    float r; asm("v_log_f32 %0, %1" : "=v"(r) : "v"(x)); return r;
}

// ---------------- Kernel 1: word pooling fused into GEMV (+ slice-min, dtype detect) ----
__global__ __launch_bounds__(256) void klogits(
    const float* __restrict__ embs, const void* __restrict__ p2w,
    const void* __restrict__ masks, const float* __restrict__ W,
    const float* __restrict__ bias, float* __restrict__ out_logits, WS* __restrict__ ws)
{
    const int bl = blockIdx.x;        // 0..511
    const int b  = bl / NL;
    const int tid = threadIdx.x;
    const int w = tid >> 6, lane = tid & 63;

    __shared__ int   plist[NP];
    __shared__ int   cnt;
    __shared__ int   isint_sh;
    __shared__ float wmin[4];

    // ---- early independent loads ----
    const float4* e4 = (const float4*)(embs + bl * 960);   // 512*960 = NB*NP*NH
    float4 mv4 = (tid < 240) ? e4[tid] : make_float4(3.0e38f, 3.0e38f, 3.0e38f, 3.0e38f);
    unsigned char pb = 0;
    if (tid < NP) pb = ((const unsigned char*)p2w)[bl * NP + tid];
    const unsigned char mkb = ((const unsigned char*)masks)[bl];

    // detect: masks word 0 (batch 0 all-true): int32 -> 1, bytes -> 0x01010101
    if (tid == 0) { isint_sh = (((const unsigned*)masks)[0] <= 1u); cnt = 0; }
    __syncthreads();
    const int is_int = isint_sh;

    int have = 0;
    if (tid < NP) have = is_int ? (((const int*)p2w)[bl * NP + tid] != 0) : (pb != 0);
    if (have) plist[atomicAdd(&cnt, 1)] = tid;   // nc <= 2 pieces/word

    float m = fminf(fminf(mv4.x, mv4.y), fminf(mv4.z, mv4.w));
    m = dpp_fmin(m);
    if (lane == 63) wmin[w] = m;

    const int mk = is_int ? (((const int*)masks)[bl] != 0) : (mkb != 0);
    __syncthreads();
    if (tid == 0) ws->part[bl] = fminf(fminf(wmin[0], wmin[1]), fminf(wmin[2], wmin[3]));

    const int nc = cnt;
    if (nc == 0) {
        // masked+empty -> word_reps = min_value (kcrf fixes); else zeros -> bias only
        if (tid == 0) ws->empty[bl] = mk ? 1 : 0;
        if (tid < NT) { float v = bias[tid]; out_logits[bl * NT + tid] = v; ws->lg[bl * NT + tid] = v; }
        return;
    }
    if (tid == 0) ws->empty[bl] = 0;

    // on-the-fly pooling: each lane's 12 h positions (coalesced per row), no LDS roundtrip
    float wr[12];
    #pragma unroll
    for (int j = 0; j < 12; j++) wr[j] = -3.0e38f;   // min_value <= all values: equivalent
    for (int i = 0; i < nc; i++) {
        const float* er = embs + (b * NP + plist[i]) * NH;
        #pragma unroll
        for (int j = 0; j < 12; j++) wr[j] = fmaxf(wr[j], er[lane + j * 64]);
    }
    const float mkf = mk ? 1.0f : 0.0f;   // exact: x*1 = x, x*0 = 0

    for (int t = w; t < NT; t += 4) {
        float acc = 0.f;
        #pragma unroll
        for (int j = 0; j < 12; j++) acc += wr[j] * W[(lane + j * 64) * NT + t];
        acc = dpp_add(acc);
        if (lane == 63) {
            float v = fmaf(mkf, acc, bias[t]);
            out_logits[bl * NT + t] = v;
            ws->lg[bl * NT + t]     = v;
        }
    }
}

// ---------------- Kernel 2: min-reduce + fixup + CRF (log2 domain, relative alpha) ----
// 1 block, 8 waves: waves 0..3 run one batch each (lanes 0..8 = tags); 4..7 help stage.
__global__ __launch_bounds__(512) void kcrf(
    const int* __restrict__ labels, const int* __restrict__ sentlen,
    const float* __restrict__ W, const float* __restrict__ bias,
    const float* __restrict__ start_t, const float* __restrict__ end_t,
    const float* __restrict__ trans, WS* __restrict__ ws, float* __restrict__ out)
{
    __shared__ float em_s[NB * NL * NT + 16];   // raw logits; pad covers prefetch overread
    __shared__ float trs[NT * NT];              // log2-scaled
    __shared__ int   lab_s[NB * NL];
    __shared__ float llh[NB];
    __shared__ float colsum[NT];
    __shared__ float wmin[8];

    const int tid  = threadIdx.x;
    const int w    = tid >> 6;
    const int lane = tid & 63;

    // (1) register-stage dependent loads (512 threads: 2.25 rounds)
    const float4* s4 = (const float4*)ws->lg;
    float4 lgA = s4[tid];
    float4 lgB = s4[tid + 512];
    float4 lgC = (tid < 128) ? s4[tid + 1024] : make_float4(0, 0, 0, 0);
    int4  labv = (tid < 128) ? ((const int4*)labels)[tid] : make_int4(0, 0, 0, 0);
    float pmv  = ws->part[tid];
    float trv  = (tid < NT * NT) ? trans[tid] : 0.f;

    // (2) write staged data
    float4* d4 = (float4*)em_s;
    d4[tid]       = lgA;
    d4[tid + 512] = lgB;
    if (tid < 128) d4[tid + 1024] = lgC;
    if (tid < 128) ((int4*)lab_s)[tid] = labv;
    if (tid < NT * NT) trs[tid] = trv * L2E;

    {   // global min from 512 partials (one per thread)
        float mv = dpp_fmin(pmv);
        if (lane == 63) wmin[w] = mv;
    }
    if (w < 4) {
        for (int t = w; t < NT; t += 4) {   // colsum(W) for minv fixup
            float s = 0.f;
            #pragma unroll
            for (int j = 0; j < 12; j++) s += W[(lane + j * 64) * NT + t];
            s = dpp_add(s);
            if (lane == 63) colsum[t] = s;
        }
    }
    __syncthreads();
    const float minv = fminf(fminf(fminf(wmin[0], wmin[1]), fminf(wmin[2], wmin[3])),
                             fminf(fminf(wmin[4], wmin[5]), fminf(wmin[6], wmin[7])));

    // fix flagged rows: minv*colsum + bias
    for (int r = tid; r < NBLK; r += 512) {
        if (ws->empty[r]) {
            #pragma unroll
            for (int t = 0; t < NT; t++) {
                float v = fmaf(minv, colsum[t], bias[t]);
                em_s[r * NT + t]    = v;
                out[1 + r * NT + t] = v;
            }
        }
    }
    __syncthreads();

    if (w < 4) {
        const int b   = w;
        const int c   = (lane < NT) ? lane : 0;     // lanes >= 9 mirror lane 0
        const int len = sentlen[b];                 // masks == arange < sent_length
        const float* em  = em_s + b * NL * NT;
        const int*   lab = lab_s + b * NL;

        // (3) numerator: fully parallel over positions
        float nsum = 0.f;
        for (int i = 1 + lane; i < len; i += 64) {
            int tp = lab[i - 1], tc = lab[i];
            nsum = fmaf(em[i * NT + tc], L2E, nsum + trs[tp * NT + tc]);
        }
        nsum = dpp_add(nsum);
        const float nsum_all = rdlane(nsum, 63);

        // (4) serial recursion — log2 domain, RELATIVE alpha (a_rel[0] == 0)
        float tcol[NT];
        #pragma unroll
        for (int p = 0; p < NT; p++) tcol[p] = trs[p * NT + c];
        const float ecol0 = exp2v(tcol[0]);     // p=0 term: exp2(a_rel[0]+T[0][c]) const

        float vini = fmaf(em[c], L2E, start_t[c] * L2E);   // absolute alpha_0[c]
        float rv0  = rdlane(vini, 0);
        float wrel = vini - rv0;                // a_rel[c] (per lane)
        float a0abs = rv0;                      // absolute alpha[0], uniform
        float r1 = rdlane(wrel, 1), r2 = rdlane(wrel, 2), r3 = rdlane(wrel, 3);
        float r4 = rdlane(wrel, 4), r5 = rdlane(wrel, 5), r6 = rdlane(wrel, 6);
        float r7 = rdlane(wrel, 7), r8 = rdlane(wrel, 8);

        float em_c = em[NT + c];
        for (int i = 1; i < len; i++) {
            float em_nx = em[(i + 1) * NT + c];   // pad covers overread at i = len-1
            float e1 = exp2v(r1 + tcol[1]);
            float e2 = exp2v(r2 + tcol[2]);
            float e3 = exp2v(r3 + tcol[3]);
            float e4 = exp2v(r4 + tcol[4]);
            float e5 = exp2v(r5 + tcol[5]);
            float e6 = exp2v(r6 + tcol[6]);
            float e7 = exp2v(r7 + tcol[7]);
            float e8 = exp2v(r8 + tcol[8]);
            float s = (((ecol0 + e1) + (e2 + e3)) + ((e4 + e5) + (e6 + e7))) + e8;
            float v = fmaf(em_c, L2E, log2v(s));  // u + em (absolute minus a0abs)
            float nv0 = rdlane(v, 0);
            wrel = v - nv0;
            r1 = rdlane(wrel, 1); r2 = rdlane(wrel, 2); r3 = rdlane(wrel, 3);
            r4 = rdlane(wrel, 4); r5 = rdlane(wrel, 5); r6 = rdlane(wrel, 6);
            r7 = rdlane(wrel, 7); r8 = rdlane(wrel, 8);
            a0abs += nv0;
            em_c = em_nx;
        }

        // (5) denominator + loss
        float xv = wrel + end_t[c] * L2E;       // relative; a0abs added below
        if (lane == 0) {
            float dv[NT];
            #pragma unroll
            for (int p = 0; p < NT; p++) dv[p] = rdlane(xv, p);
            float mx = fmaxf(fmaxf(fmaxf(dv[0], dv[1]), dv[2]),
                             fmaxf(fmaxf(fmaxf(dv[3], dv[4]), dv[5]),
                                   fmaxf(fmaxf(dv[6], dv[7]), dv[8])));
            float s = 0.f;
            #pragma unroll
            for (int p = 0; p < NT; p++) s += exp2v(dv[p] - mx);
            float den = a0abs + mx + log2v(s);
            int   t0  = lab[0];
            float num = fmaf(em[t0], L2E, nsum_all + start_t[t0] * L2E + end_t[lab[len - 1]] * L2E);
            llh[b] = (num - den) * LN2;
        }
    }
    __syncthreads();
    if (tid == 0) out[0] = -(llh[0] + llh[1] + llh[2] + llh[3]);
}

extern "C" void kernel_launch(void* const* d_in, const int* in_sizes, int n_in,
                              void* d_out, int out_size, void* d_ws, size_t ws_size,
                              hipStream_t stream) {
    const float* embs    = (const float*)d_in[0];
    const void*  p2w     = d_in[1];
    const void*  masks   = d_in[2];
    const int*   labels  = (const int*)d_in[3];
    const int*   sentlen = (const int*)d_in[4];
    const float* W       = (const float*)d_in[5];
    const float* bias    = (const float*)d_in[6];
    const float* start_t = (const float*)d_in[7];
    const float* end_t   = (const float*)d_in[8];
    const float* trans   = (const float*)d_in[9];

    float* out = (float*)d_out;        // out[0] = loss, out[1..] = logits (B,L,T)
    WS*    ws  = (WS*)d_ws;

    klogits<<<NBLK, 256, 0, stream>>>(embs, p2w, masks, W, bias, out + 1, ws);
    kcrf<<<1, 512, 0, stream>>>(labels, sentlen, W, bias, start_t, end_t, trans, ws, out);
}